// Round 1
// baseline (86.208 us; speedup 1.0000x reference)
//
#include <hip/hip_runtime.h>
#include <math.h>

// QuanvolutionHybrid: the reference only consumes feats[:, :1] == <Z_0> of
// patch 0 of each image. So per batch element we simulate ONE 4-qubit circuit
// (16 complex amps in registers), then a 1-qubit chain, then Linear(1,10) +
// log_softmax. One thread per image, B=4096 threads total.

struct c32 { float re, im; };

__device__ __forceinline__ c32 cmul(c32 a, c32 b) {
    return { fmaf(a.re, b.re, -a.im * b.im), fmaf(a.re, b.im, a.im * b.re) };
}
__device__ __forceinline__ c32 cadd(c32 a, c32 b) { return { a.re + b.re, a.im + b.im }; }

// Apply 2x2 gate U on wire W of a 4-wire state. Wire w's bit stride = 8>>w
// (state index = b0*8 + b1*4 + b2*2 + b3, axis 1+w of the [2,2,2,2] tensor).
template<int W>
__device__ __forceinline__ void apply1(c32 amp[16], c32 u00, c32 u01, c32 u10, c32 u11) {
    constexpr int s = 8 >> W;
    #pragma unroll
    for (int i = 0; i < 16; ++i) {
        if (i & s) continue;  // constant-folded after unroll
        c32 a = amp[i], b = amp[i + s];
        amp[i]     = cadd(cmul(u00, a), cmul(u01, b));
        amp[i + s] = cadd(cmul(u10, a), cmul(u11, b));
    }
}

template<int C, int T>
__device__ __forceinline__ void cnot4(c32 amp[16]) {
    constexpr int sc = 8 >> C, st = 8 >> T;
    #pragma unroll
    for (int i = 0; i < 16; ++i) {
        if ((i & sc) && !(i & st)) {  // control=1, target=0: swap with target=1
            c32 tmp = amp[i]; amp[i] = amp[i | st]; amp[i | st] = tmp;
        }
    }
}

// PennyLane Rot(phi, theta, omega) = RZ(omega) RY(theta) RZ(phi)
__device__ __forceinline__ void make_rot(float phi, float th, float om,
                                         c32& u00, c32& u01, c32& u10, c32& u11) {
    float sh, ch; sincosf(th * 0.5f, &sh, &ch);
    float spo, cpo; sincosf((phi + om) * 0.5f, &spo, &cpo);
    float spm, cpm; sincosf((phi - om) * 0.5f, &spm, &cpm);
    u00 = {  cpo * ch, -spo * ch };  // e^{-i(phi+om)/2} cos(th/2)
    u01 = { -cpm * sh, -spm * sh };  // -e^{+i(phi-om)/2} sin(th/2)
    u10 = {  cpm * sh, -spm * sh };  // e^{-i(phi-om)/2} sin(th/2)
    u11 = {  cpo * ch,  spo * ch };  // e^{+i(phi+om)/2} cos(th/2)
}

template<int W>
__device__ __forceinline__ void rx_apply(c32 amp[16], float ang) {
    float s, c; sincosf(ang * 0.5f, &s, &c);
    apply1<W>(amp, c32{c, 0.f}, c32{0.f, -s}, c32{0.f, -s}, c32{c, 0.f});
}

template<int W>
__device__ __forceinline__ void rot_apply(c32 amp[16], const float* p) {
    c32 a, b, c, d;
    make_rot(p[0], p[1], p[2], a, b, c, d);
    apply1<W>(amp, a, b, c, d);
}

__global__ __launch_bounds__(64)
void quanv_hybrid_kernel(const float* __restrict__ x,
                         const float* __restrict__ wq,    // [2,2,4,3]
                         const float* __restrict__ wfc,   // [3,3,1,3]
                         const float* __restrict__ Wout,  // [10,1]
                         const float* __restrict__ bout,  // [10]
                         float* __restrict__ out,         // [B,10]
                         int B)
{
    int b = blockIdx.x * blockDim.x + threadIdx.x;
    if (b >= B) return;

    // Patch 0 of image b: img[0,0], img[0,1], img[1,0], img[1,1]
    const float* xb = x + (size_t)b * 784;
    float ang0 = xb[0], ang1 = xb[1], ang2 = xb[28], ang3 = xb[29];

    // |0000>
    c32 amp[16];
    #pragma unroll
    for (int i = 0; i < 16; ++i) amp[i] = { 0.f, 0.f };
    amp[0].re = 1.f;

    // AngleEmbedding: RX(patch[w]) on wire w
    rx_apply<0>(amp, ang0);
    rx_apply<1>(amp, ang1);
    rx_apply<2>(amp, ang2);
    rx_apply<3>(amp, ang3);

    // StronglyEntanglingLayers: 2 apps x 2 layers; ranges = (1, 2)
    #pragma unroll
    for (int al = 0; al < 4; ++al) {          // al = app*2 + l
        const float* wp = wq + al * 12;       // 4 wires x 3 params
        rot_apply<0>(amp, wp + 0);
        rot_apply<1>(amp, wp + 3);
        rot_apply<2>(amp, wp + 6);
        rot_apply<3>(amp, wp + 9);
        if ((al & 1) == 0) {                  // layer 0: r = 1
            cnot4<0,1>(amp); cnot4<1,2>(amp); cnot4<2,3>(amp); cnot4<3,0>(amp);
        } else {                              // layer 1: r = 2
            cnot4<0,2>(amp); cnot4<1,3>(amp); cnot4<2,0>(amp); cnot4<3,1>(amp);
        }
    }

    // <Z_0> = P(bit0=0) - P(bit0=1); bit0 is the MSB (stride 8)
    float p0 = 0.f, p1 = 0.f;
    #pragma unroll
    for (int i = 0; i < 16; ++i) {
        float p = fmaf(amp[i].re, amp[i].re, amp[i].im * amp[i].im);
        if (i < 8) p0 += p; else p1 += p;
    }
    float z0 = p0 - p1;

    // qfc: 1-qubit RX(z0)|0> then 9 shared Rot gates (3 apps x 3 layers)
    float sh, chh; sincosf(z0 * 0.5f, &sh, &chh);
    c32 psi0 = { chh, 0.f }, psi1 = { 0.f, -sh };
    #pragma unroll
    for (int g = 0; g < 9; ++g) {
        const float* p = wfc + g * 3;
        c32 u00, u01, u10, u11;
        make_rot(p[0], p[1], p[2], u00, u01, u10, u11);
        c32 n0 = cadd(cmul(u00, psi0), cmul(u01, psi1));
        c32 n1 = cadd(cmul(u10, psi0), cmul(u11, psi1));
        psi0 = n0; psi1 = n1;
    }
    float q = (psi0.re * psi0.re + psi0.im * psi0.im)
            - (psi1.re * psi1.re + psi1.im * psi1.im);

    // Linear(1,10) + log_softmax
    float lg[10], m = -1e30f;
    #pragma unroll
    for (int j = 0; j < 10; ++j) {
        lg[j] = fmaf(q, Wout[j], bout[j]);
        m = fmaxf(m, lg[j]);
    }
    float sum = 0.f;
    #pragma unroll
    for (int j = 0; j < 10; ++j) sum += expf(lg[j] - m);
    float lse = m + logf(sum);

    float* ob = out + (size_t)b * 10;
    #pragma unroll
    for (int j = 0; j < 10; ++j) ob[j] = lg[j] - lse;
}

extern "C" void kernel_launch(void* const* d_in, const int* in_sizes, int n_in,
                              void* d_out, int out_size, void* d_ws, size_t ws_size,
                              hipStream_t stream) {
    const float* x    = (const float*)d_in[0];
    const float* wq   = (const float*)d_in[1];
    const float* wfc  = (const float*)d_in[2];
    const float* Wout = (const float*)d_in[3];
    const float* bout = (const float*)d_in[4];
    float* out = (float*)d_out;

    int B = in_sizes[0] / 784;  // 4096
    const int threads = 64;     // one wave per block -> 64 blocks across CUs
    int blocks = (B + threads - 1) / threads;
    quanv_hybrid_kernel<<<blocks, threads, 0, stream>>>(x, wq, wfc, Wout, bout, out, B);
}